// Round 5
// baseline (162.628 us; speedup 1.0000x reference)
//
#include <hip/hip_runtime.h>
#include <hip/hip_bf16.h>

typedef __attribute__((ext_vector_type(4))) float f32x4;
typedef __attribute__((ext_vector_type(8))) short bf16x8;
typedef __attribute__((ext_vector_type(4))) short s16x4;
typedef __attribute__((ext_vector_type(4))) unsigned int u32x4;

#define DEV static __device__ __forceinline__

// fp32 -> bf16 round-to-nearest-even (finite values only)
DEV unsigned short f2b(float f) {
  union { float f; unsigned int u; } v; v.f = f;
  unsigned int u = v.u;
  return (unsigned short)((u + 0x7fffu + ((u >> 16) & 1u)) >> 16);
}

// async global->LDS, 16B per lane; lds base wave-uniform, lanes land at base + lane*16
DEV void gll16(const void* g, void* l) {
  __builtin_amdgcn_global_load_lds((__attribute__((address_space(1))) void*)g,
                                   (__attribute__((address_space(3))) void*)l,
                                   16, 0, 0);
}

// ---------------------------------------------------------------------------
// prep: fp32 -> bf16 conversion + weight repack (unchanged from round 4).
// Blocks 0..8191: x conversion (f32x4 -> s16x4, coalesced).
// Blocks 8192..8383: Wt tiles (LDS-tiled transpose, coalesced both sides).
// Blocks 8384..8447: WoT tiles.
// ---------------------------------------------------------------------------
__global__ __launch_bounds__(256) void prep(const float* __restrict__ x,
                                            const float* __restrict__ Wq,
                                            const float* __restrict__ Wk,
                                            const float* __restrict__ Wv,
                                            const float* __restrict__ Wo,
                                            unsigned short* __restrict__ xb,
                                            unsigned short* __restrict__ Wt,
                                            unsigned short* __restrict__ WoT) {
  const int bid = blockIdx.x;
  if (bid < 8192) {                                    // x: 8388608 elems / 4
    int id = bid * 256 + threadIdx.x;
    f32x4 v = *(const f32x4*)(x + (long)id * 4);
    s16x4 o;
    o.x = (short)f2b(v.x); o.y = (short)f2b(v.y);
    o.z = (short)f2b(v.z); o.w = (short)f2b(v.w);
    *(s16x4*)(xb + (long)id * 4) = o;
    return;
  }

  __shared__ unsigned int L[64 * 65];
  const int tx = threadIdx.x & 63;     // fast index (coalesced axis)
  const int ty = threadIdx.x >> 6;     // wave id: 4 rows in flight

  int tb = bid - 8192;
  if (tb < 192) {
    // Wt[n][c] = W[h][c][d], n = proj*512 + h*64 + d. Tile: full d (64) x 64 c.
    int proj = tb >> 6, h = (tb >> 3) & 7, c0 = (tb & 7) << 6;
    const float* W = (proj == 0) ? Wq : ((proj == 1) ? Wk : Wv);
    const float* base = W + (long)h * 32768 + (long)c0 * 64;  // [c][d]
#pragma unroll
    for (int i = 0; i < 16; i++) {
      int c = ty + i * 4;                               // per-wave row; tx = d
      L[tx * 65 + c] = f2b(base[(long)c * 64 + tx]);    // L[d][c]
    }
    __syncthreads();
    unsigned short* out = Wt + ((long)(proj * 512 + h * 64)) * 512 + c0;
#pragma unroll
    for (int i = 0; i < 16; i++) {
      int d = ty + i * 4;                               // tx = c_local
      out[(long)d * 512 + tx] = (unsigned short)L[d * 65 + tx];
    }
  } else {
    // WoT[n][c] = Wo[c][n]. Tile 64 n x 64 c.
    int t = tb - 192;
    int n0 = (t >> 3) << 6, c0 = (t & 7) << 6;
#pragma unroll
    for (int i = 0; i < 16; i++) {
      int c = ty + i * 4;                               // tx = n_local
      L[tx * 65 + c] = f2b(Wo[(long)(c0 + c) * 512 + n0 + tx]);  // L[n][c]
    }
    __syncthreads();
    unsigned short* out = WoT + (long)n0 * 512 + c0;
#pragma unroll
    for (int i = 0; i < 16; i++) {
      int n = ty + i * 4;                               // tx = c_local
      out[(long)n * 512 + tx] = (unsigned short)L[n * 65 + tx];
    }
  }
}

// ---------------------------------------------------------------------------
// C[M x N] = A[M x 512] * BT[N x 512]^T   (bf16 in, fp32 accum)
// Round 8: deep-pipelined 8-wave template (T3+T4+T5 structure, re-dimensioned
// for K=512). BM=128, BN=256, BK=64, 512 threads (2M x 4N waves, 64x64 out
// per wave, acc[4][4]). LDS 96 KB: K-tile double buffer (A 16 KB + B 32 KB
// per tile). Grid: gemm1 768 = 3 exact CU-rounds; gemm2 256 = 1 round.
//
// Per K-tile kt (compute buf bc = kt&1, stage buf bs = bc^1, 6 gll16/tile):
//   s_barrier            (WAR: all waves' kt-1 reads consumed pre-arrival)
//   stage S0(kt+1) 2x    (safe: buffer bs's readers all passed barrier)
//   s_waitcnt vmcnt(2)   (counted: drains kt's 6, issued one K-tile ago ~400+
//                         cyc flight; NEVER a drain of just-issued loads)
//   s_barrier            (RAW: every wave's kt stages landed)
//   setprio(1); kc=0 slice [8 ds_read_b128 + 16 MFMA]; stage S1(kt+1) 2x;
//               kc=1 slice; stage S2(kt+1) 2x; setprio(0)
// Tail kt=7: no stages, vmcnt(0) (loads one K-tile old — near-free).
// sched_barrier(0) after each raw barrier + asm memory clobbers fence
// ds_read/gll16 motion across the sync points.
// Swizzle: same verified cg^(row&7) family (0 bank conflicts measured).
// XCD-bijective swizzle, bn-fast (A-panel reuse within one XCD L2).
// ---------------------------------------------------------------------------
template <int F32OUT>
__global__ __launch_bounds__(512, 2) void gemm_bt(const unsigned short* __restrict__ A,
                                                  const unsigned short* __restrict__ BT,
                                                  void* __restrict__ Cv,
                                                  int N) {
  const int K = 512;
  __shared__ unsigned short Ash[2][128 * 64];   // 2 x 16 KB
  __shared__ unsigned short Bsh[2][256 * 64];   // 2 x 32 KB

  const int tid = threadIdx.x;
  const int wave = tid >> 6, lane = tid & 63;
  const int quad = lane >> 4, l16 = lane & 15;
  const int wm = wave >> 2, wn = wave & 3;      // 2M x 4N wave grid

  // bijective XCD swizzle, bn-fast inside each XCD chunk
  const int NB = N >> 8;                        // 256-wide N tiles
  const int nwg = gridDim.x;
  const int q = nwg >> 3, r = nwg & 7;
  const int xcd = blockIdx.x & 7, ci = blockIdx.x >> 3;
  const int wg = (xcd < r ? xcd * (q + 1) : r * (q + 1) + (xcd - r) * q) + ci;
  const int bn = wg % NB;
  const int bm = wg / NB;

  // staging geometry: one issue = 64 rows (8 rows/wave, 8 lanes/row).
  // lane -> row wave*8 + (lane>>3), fetches global col-group (lane&7)^(row&7),
  // lands at lds slot lane&7 (gll16 base + lane*16 identity).
  const int r8 = lane >> 3, cg = lane & 7;
  const int gc = (cg ^ r8) * 8;

  const unsigned short* Abase = A + (long)(bm * 128 + wave * 8 + r8) * K + gc;
  const unsigned short* Bbase = BT + (long)(bn * 256 + wave * 8 + r8) * K + gc;

  f32x4 acc[4][4] = {};

  auto stageA = [&](int kt, int buf, int issue) {
    gll16(Abase + (long)issue * 64 * K + kt * 64,
          &Ash[buf][(issue * 64 + wave * 8) * 64]);
  };
  auto stageB = [&](int kt, int buf, int issue) {
    gll16(Bbase + (long)issue * 64 * K + kt * 64,
          &Bsh[buf][(issue * 64 + wave * 8) * 64]);
  };

  auto kslice = [&](int buf, int kc) {
    bf16x8 af[4], bfv[4];
#pragma unroll
    for (int mt = 0; mt < 4; mt++) {
      int rr = wm * 64 + mt * 16 + l16;
      af[mt] = *(const bf16x8*)(&Ash[buf][rr * 64 + (((kc * 4 + quad) ^ (rr & 7)) * 8)]);
    }
#pragma unroll
    for (int nt = 0; nt < 4; nt++) {
      int rb = wn * 64 + nt * 16 + l16;
      bfv[nt] = *(const bf16x8*)(&Bsh[buf][rb * 64 + (((kc * 4 + quad) ^ (rb & 7)) * 8)]);
    }
#pragma unroll
    for (int mt = 0; mt < 4; mt++)
#pragma unroll
      for (int nt = 0; nt < 4; nt++)
        acc[mt][nt] = __builtin_amdgcn_mfma_f32_16x16x32_bf16(af[mt], bfv[nt], acc[mt][nt], 0, 0, 0);
  };

  // prologue: stage all of kt=0 into buf 0 (6 issues)
  stageB(0, 0, 0); stageB(0, 0, 1); stageB(0, 0, 2); stageB(0, 0, 3);
  stageA(0, 0, 0); stageA(0, 0, 1);

#pragma unroll
  for (int kt = 0; kt < 8; kt++) {
    const int bc = kt & 1, bs = bc ^ 1;
    __builtin_amdgcn_s_barrier();              // WAR gate: bs's readers done
    __builtin_amdgcn_sched_barrier(0);
    if (kt < 7) { stageB(kt + 1, bs, 0); stageB(kt + 1, bs, 1); }
    if (kt < 7) asm volatile("s_waitcnt vmcnt(2)" ::: "memory");
    else        asm volatile("s_waitcnt vmcnt(0)" ::: "memory");
    __builtin_amdgcn_s_barrier();              // RAW gate: kt landed everywhere
    __builtin_amdgcn_sched_barrier(0);
    __builtin_amdgcn_s_setprio(1);
    kslice(bc, 0);
    if (kt < 7) { stageB(kt + 1, bs, 2); stageB(kt + 1, bs, 3); }
    kslice(bc, 1);
    if (kt < 7) { stageA(kt + 1, bs, 0); stageA(kt + 1, bs, 1); }
    __builtin_amdgcn_s_setprio(0);
  }

  // epilogue: D elem (row = quad*4 + r2, col = l16) within each 16x16 tile
#pragma unroll
  for (int mt = 0; mt < 4; mt++) {
#pragma unroll
    for (int nt = 0; nt < 4; nt++) {
      int row0 = bm * 128 + wm * 64 + mt * 16 + quad * 4;
      int col = bn * 256 + wn * 64 + nt * 16 + l16;
      if (F32OUT) {
        float* cp = (float*)Cv + (long)row0 * N + col;
#pragma unroll
        for (int r2 = 0; r2 < 4; r2++)
          cp[(long)r2 * N] = acc[mt][nt][r2];
      } else {
        unsigned short* cp = (unsigned short*)Cv + (long)row0 * N + col;
#pragma unroll
        for (int r2 = 0; r2 < 4; r2++)
          cp[(long)r2 * N] = f2b(acc[mt][nt][r2]);
      }
    }
  }
}

// ---------------------------------------------------------------------------
// Causal attention, one block per (b,h). QKV: [16384][1536] bf16.
// All 256 K-rows + V staged ONCE (one barrier), then wave w independently
// processes 32-row q-tile pair {w, 7-w}: (w+1)+(8-w) = 9 chunk-32s per wave.
// Kl: packed rows, global-side XOR swizzle (gll16-compatible). Vt: rows
// padded to 264 shorts. Pl: stride 40. Fixed-shift softmax (p = exp(s),
// fp32 row-sum normalize at end) — validated absmax 0.0156.
// ---------------------------------------------------------------------------
__global__ __launch_bounds__(256, 2) void attn(const unsigned short* __restrict__ QKV,
                                               unsigned short* __restrict__ AO) {
  const int bh = blockIdx.x;
  const int b = bh >> 3, h = bh & 7;
  const int tid = threadIdx.x;
  const int wave = tid >> 6, lane = tid & 63;
  const int quad = lane >> 4, l16 = lane & 15;

  __shared__ unsigned short Kl[256 * 64];    // [j][cg], stored cg holds global cg^(j&7)
  __shared__ unsigned short Vt[64 * 264];    // [d][j], padded rows
  __shared__ unsigned short Pl[4][32 * 40];  // per-wave P [trow][col], padded

  const unsigned short* Qb = QKV + (long)b * 256 * 1536 + h * 64;
  const unsigned short* Kb = Qb + 512;
  const unsigned short* Vb = Qb + 1024;

  // ---- stage K: 32 segs x 8 rows, gll16 with global-side swizzle ----
  {
    int r = lane >> 3, cg = lane & 7;
#pragma unroll
    for (int s = 0; s < 8; s++) {
      int seg = wave * 8 + s;
      gll16(Kb + (long)(seg * 8 + r) * 1536 + ((cg ^ r) * 8), Kl + seg * 512);
    }
  }
  // ---- stage V transposed: thread tid owns V row j=tid ----
  {
    int j = tid;
    const unsigned short* vp = Vb + (long)j * 1536;
#pragma unroll
    for (int g = 0; g < 8; g++) {
      union { u32x4 v; unsigned short s[8]; } d;
      d.v = *(const u32x4*)(vp + g * 8);
#pragma unroll
      for (int q = 0; q < 8; q++)
        Vt[(g * 8 + q) * 264 + j] = d.s[q];
    }
  }
  // ---- Q fragments for this wave's tile pair ----
  const int tiles[2] = {wave, 7 - wave};
  bf16x8 qf[2][2][2];  // [ti][kc][mt]
#pragma unroll
  for (int ti = 0; ti < 2; ti++)
#pragma unroll
    for (int kc = 0; kc < 2; kc++)
#pragma unroll
      for (int mt = 0; mt < 2; mt++)
        qf[ti][kc][mt] = *(const bf16x8*)(Qb +
            (long)(tiles[ti] * 32 + mt * 16 + l16) * 1536 + kc * 32 + quad * 8);

  __syncthreads();  // drains gll16 vmcnt + V/Q visibility; the ONLY barrier

  f32x4 O[2][2][4] = {};      // [ti][mt][dt]
  float lsum[2][2][4] = {};   // [ti][mt][r]
  const float scale = 0.044194173824159216f;  // 1/sqrt(512)

#pragma unroll
  for (int ti = 0; ti < 2; ti++) {
    const int t = tiles[ti];
    for (int c32 = 0; c32 <= t; c32++) {       // wave-uniform trip count
      // ---- S = Q K^T for 32 rows x 32 cols ----
      f32x4 S[2][2] = {};                      // [mt][st]
#pragma unroll
      for (int kc = 0; kc < 2; kc++) {
        bf16x8 kbf[2];
#pragma unroll
        for (int st = 0; st < 2; st++) {
          int jrow = c32 * 32 + st * 16 + l16;
          kbf[st] = *(const bf16x8*)(Kl + jrow * 64 + (((kc * 4 + quad) ^ (jrow & 7)) * 8));
        }
#pragma unroll
        for (int mt = 0; mt < 2; mt++)
#pragma unroll
          for (int st = 0; st < 2; st++)
            S[mt][st] = __builtin_amdgcn_mfma_f32_16x16x32_bf16(qf[ti][kc][mt], kbf[st], S[mt][st], 0, 0, 0);
      }
      // ---- softmax numerator, P -> LDS (C-layout -> row-major) ----
      const bool diag = (c32 == t);
#pragma unroll
      for (int mt = 0; mt < 2; mt++)
#pragma unroll
        for (int st = 0; st < 2; st++)
#pragma unroll
          for (int r = 0; r < 4; r++) {
            int trow = mt * 16 + quad * 4 + r;         // row within 32-row tile
            float p = __expf(S[mt][st][r] * scale);
            if (diag && (st * 16 + l16 > trow)) p = 0.0f;
            lsum[ti][mt][r] += p;
            Pl[wave][trow * 40 + st * 16 + l16] = f2b(p);
          }
      // ---- O += P V  (same-wave LDS RAW: compiler lgkmcnt, no barrier) ----
      bf16x8 pa[2], vbf[4];
#pragma unroll
      for (int mt = 0; mt < 2; mt++)
        pa[mt] = *(const bf16x8*)(&Pl[wave][(mt * 16 + l16) * 40 + quad * 8]);
#pragma unroll
      for (int dt = 0; dt < 4; dt++)
        vbf[dt] = *(const bf16x8*)(Vt + (dt * 16 + l16) * 264 + c32 * 32 + quad * 8);
#pragma unroll
      for (int mt = 0; mt < 2; mt++)
#pragma unroll
        for (int dt = 0; dt < 4; dt++)
          O[ti][mt][dt] = __builtin_amdgcn_mfma_f32_16x16x32_bf16(pa[mt], vbf[dt], O[ti][mt][dt], 0, 0, 0);
    }
  }

  // ---- normalize by row sum (16 lanes of a quad hold one row's 16 cols) ----
  float linv[2][2][4];
#pragma unroll
  for (int ti = 0; ti < 2; ti++)
#pragma unroll
    for (int mt = 0; mt < 2; mt++)
#pragma unroll
      for (int r = 0; r < 4; r++) {
        float s = lsum[ti][mt][r];
        s += __shfl_xor(s, 1); s += __shfl_xor(s, 2);
        s += __shfl_xor(s, 4); s += __shfl_xor(s, 8);
        linv[ti][mt][r] = 1.0f / s;
      }
#pragma unroll
  for (int ti = 0; ti < 2; ti++)
#pragma unroll
    for (int mt = 0; mt < 2; mt++)
#pragma unroll
      for (int dt = 0; dt < 4; dt++)
#pragma unroll
        for (int r = 0; r < 4; r++) {
          int t_ = tiles[ti] * 32 + mt * 16 + quad * 4 + r;
          int d = dt * 16 + l16;
          AO[(long)(b * 256 + t_) * 512 + h * 64 + d] = f2b(O[ti][mt][dt][r] * linv[ti][mt][r]);
        }
}

// ---------------------------------------------------------------------------
extern "C" void kernel_launch(void* const* d_in, const int* in_sizes, int n_in,
                              void* d_out, int out_size, void* d_ws, size_t ws_size,
                              hipStream_t stream) {
  const float* x  = (const float*)d_in[0];   // [16384][512] fp32
  const float* Wq = (const float*)d_in[1];   // [8][512][64] fp32
  const float* Wk = (const float*)d_in[2];
  const float* Wv = (const float*)d_in[3];
  const float* Wo = (const float*)d_in[4];   // [512][512] fp32

  unsigned short* Wt  = (unsigned short*)d_ws;                 // 1536*512
  unsigned short* WoT = Wt + 1536 * 512;                       // 512*512
  unsigned short* xb  = WoT + 512 * 512;                       // 16384*512
  unsigned short* QKV = xb + (long)16384 * 512;                // 16384*1536
  unsigned short* AO  = QKV + (long)16384 * 1536;              // 16384*512
  float* out = (float*)d_out;                                  // [16384][512] fp32

  prep<<<8448, 256, 0, stream>>>(x, Wq, Wk, Wv, Wo, xb, Wt, WoT);

  gemm_bt<0><<<768, 512, 0, stream>>>(xb, Wt, (void*)QKV, 1536);

  attn<<<512, 256, 0, stream>>>(QKV, AO);

  gemm_bt<1><<<256, 512, 0, stream>>>(AO, WoT, (void*)out, 512);
}

// Round 6
// 156.279 us; speedup vs baseline: 1.0406x; 1.0406x over previous
//
#include <hip/hip_runtime.h>
#include <hip/hip_bf16.h>

typedef __attribute__((ext_vector_type(4))) float f32x4;
typedef __attribute__((ext_vector_type(8))) short bf16x8;
typedef __attribute__((ext_vector_type(4))) short s16x4;
typedef __attribute__((ext_vector_type(4))) unsigned int u32x4;

#define DEV static __device__ __forceinline__

// fp32 -> bf16 round-to-nearest-even (finite values only)
DEV unsigned short f2b(float f) {
  union { float f; unsigned int u; } v; v.f = f;
  unsigned int u = v.u;
  return (unsigned short)((u + 0x7fffu + ((u >> 16) & 1u)) >> 16);
}

// async global->LDS, 16B per lane; lds base wave-uniform, lanes land at base + lane*16
DEV void gll16(const void* g, void* l) {
  __builtin_amdgcn_global_load_lds((__attribute__((address_space(1))) void*)g,
                                   (__attribute__((address_space(3))) void*)l,
                                   16, 0, 0);
}

// ---------------------------------------------------------------------------
// prep: fp32 -> bf16 conversion + weight repack (round-1 exact).
// Blocks 0..8191: x conversion (f32x4 -> s16x4, coalesced).
// Blocks 8192..8383: Wt tiles (LDS-tiled transpose, coalesced both sides).
// Blocks 8384..8447: WoT tiles.
// ---------------------------------------------------------------------------
__global__ __launch_bounds__(256) void prep(const float* __restrict__ x,
                                            const float* __restrict__ Wq,
                                            const float* __restrict__ Wk,
                                            const float* __restrict__ Wv,
                                            const float* __restrict__ Wo,
                                            unsigned short* __restrict__ xb,
                                            unsigned short* __restrict__ Wt,
                                            unsigned short* __restrict__ WoT) {
  const int bid = blockIdx.x;
  if (bid < 8192) {                                    // x: 8388608 elems / 4
    int id = bid * 256 + threadIdx.x;
    f32x4 v = *(const f32x4*)(x + (long)id * 4);
    s16x4 o;
    o.x = (short)f2b(v.x); o.y = (short)f2b(v.y);
    o.z = (short)f2b(v.z); o.w = (short)f2b(v.w);
    *(s16x4*)(xb + (long)id * 4) = o;
    return;
  }

  __shared__ unsigned int L[64 * 65];
  const int tx = threadIdx.x & 63;     // fast index (coalesced axis)
  const int ty = threadIdx.x >> 6;     // wave id: 4 rows in flight

  int tb = bid - 8192;
  if (tb < 192) {
    // Wt[n][c] = W[h][c][d], n = proj*512 + h*64 + d. Tile: full d (64) x 64 c.
    int proj = tb >> 6, h = (tb >> 3) & 7, c0 = (tb & 7) << 6;
    const float* W = (proj == 0) ? Wq : ((proj == 1) ? Wk : Wv);
    const float* base = W + (long)h * 32768 + (long)c0 * 64;  // [c][d]
#pragma unroll
    for (int i = 0; i < 16; i++) {
      int c = ty + i * 4;                               // per-wave row; tx = d
      L[tx * 65 + c] = f2b(base[(long)c * 64 + tx]);    // L[d][c]
    }
    __syncthreads();
    unsigned short* out = Wt + ((long)(proj * 512 + h * 64)) * 512 + c0;
#pragma unroll
    for (int i = 0; i < 16; i++) {
      int d = ty + i * 4;                               // tx = c_local
      out[(long)d * 512 + tx] = (unsigned short)L[d * 65 + tx];
    }
  } else {
    // WoT[n][c] = Wo[c][n]. Tile 64 n x 64 c.
    int t = tb - 192;
    int n0 = (t >> 3) << 6, c0 = (t & 7) << 6;
#pragma unroll
    for (int i = 0; i < 16; i++) {
      int c = ty + i * 4;                               // tx = n_local
      L[tx * 65 + c] = f2b(Wo[(long)(c0 + c) * 512 + n0 + tx]);  // L[n][c]
    }
    __syncthreads();
    unsigned short* out = WoT + (long)n0 * 512 + c0;
#pragma unroll
    for (int i = 0; i < 16; i++) {
      int n = ty + i * 4;                               // tx = c_local
      out[(long)n * 512 + tx] = (unsigned short)L[n * 65 + tx];
    }
  }
}

// ---------------------------------------------------------------------------
// C[M x N] = A[M x 512] * BT[N x 512]^T   (bf16 in, fp32 accum)
// Round 9: round-1 structure + the catalog's "minimum 2-phase" recipe
// (T3 minimal form, m248v2 +10% same-probe):
//   prologue: STAGE(buf0, t0); vmcnt(0); barrier;
//   iter t:   STAGE(buf^1, t+1)  [fire-and-forget gll16, issued FIRST]
//             compute(buf)       [ds_read + lgkm waits + 32 MFMA]
//             vmcnt(0); barrier  [drains loads issued a full compute ago]
// vs round-1: the per-iteration drain now waits on ~700-cyc-old loads, not
// 0-cycle-old ones. vs round-2's failed dbuf: staging is pure gll16 (no
// reg-stage waits), 256 threads, 128^2 tile. LDS 64 KB -> 2 blocks/CU
// (8 waves/CU, the m230-blessed 2ph config).
// Hazards: WAR — stage(buf^1) issued only after barrier(t-1) retired all
// reads of buf^1; RAW — vmcnt(0)+barrier before flip.
// Swizzle + XCD-bijective bn-fast mapping unchanged (0 conflicts measured).
// ---------------------------------------------------------------------------
template <int F32OUT>
__global__ __launch_bounds__(256, 2) void gemm_bt(const unsigned short* __restrict__ A,
                                                  const unsigned short* __restrict__ BT,
                                                  void* __restrict__ Cv,
                                                  int N) {
  const int K = 512;
  __shared__ unsigned short As[2][128 * 64];
  __shared__ unsigned short Bs[2][128 * 64];

  const int tid = threadIdx.x;
  const int wave = tid >> 6, lane = tid & 63;
  const int quad = lane >> 4, l16 = lane & 15;
  const int wm = wave >> 1, wn = wave & 1;

  // bijective XCD swizzle, bn-fast inside each XCD chunk
  const int NB = N >> 7;
  const int nwg = gridDim.x;
  const int q = nwg >> 3, r = nwg & 7;
  const int xcd = blockIdx.x & 7, ci = blockIdx.x >> 3;
  const int wg = (xcd < r ? xcd * (q + 1) : r * (q + 1) + (xcd - r) * q) + ci;
  const int bn = wg % NB;
  const int bm = wg / NB;

  // gll16 staging: lane i -> row i>>3 of its 8-row seg, fetches global
  // col-group (i&7)^(row&7), lands at lds cg i&7 (base + lane*16 identity).
  const int srow = lane >> 3;
  const int scol = ((lane & 7) ^ srow) * 8;

  f32x4 acc[4][4] = {};

  auto stage = [&](int kk, int buf) {
#pragma unroll
    for (int s = 0; s < 4; s++) {
      int seg = wave * 4 + s;                       // 16 segs x 8 rows = 128 rows
      int row = seg * 8 + srow;
      gll16(A + (long)(bm * 128 + row) * K + kk + scol, &As[buf][seg * 512]);
      gll16(BT + (long)(bn * 128 + row) * K + kk + scol, &Bs[buf][seg * 512]);
    }
  };

  auto compute = [&](int buf) {
#pragma unroll
    for (int kc = 0; kc < 2; kc++) {
      const int rq = (((kc * 4 + quad) ^ (l16 & 7)) * 8);  // un-swizzle for reader
      bf16x8 af[4], bfv[4];
#pragma unroll
      for (int mt = 0; mt < 4; mt++)
        af[mt] = *(const bf16x8*)(&As[buf][(wm * 64 + mt * 16 + l16) * 64 + rq]);
#pragma unroll
      for (int nt = 0; nt < 4; nt++)
        bfv[nt] = *(const bf16x8*)(&Bs[buf][(wn * 64 + nt * 16 + l16) * 64 + rq]);
#pragma unroll
      for (int mt = 0; mt < 4; mt++)
#pragma unroll
        for (int nt = 0; nt < 4; nt++)
          acc[mt][nt] = __builtin_amdgcn_mfma_f32_16x16x32_bf16(af[mt], bfv[nt], acc[mt][nt], 0, 0, 0);
    }
  };

  // prologue: tile 0 into buf 0, drained and published
  stage(0, 0);
  asm volatile("s_waitcnt vmcnt(0)" ::: "memory");
  __builtin_amdgcn_s_barrier();
  __builtin_amdgcn_sched_barrier(0);

  int cur = 0;
#pragma unroll
  for (int t = 0; t < 8; t++) {
    if (t < 7) stage((t + 1) * 64, cur ^ 1);     // issue next tile FIRST
    __builtin_amdgcn_sched_barrier(0);           // pin issues above compute
    compute(cur);
    if (t < 7) {
      asm volatile("s_waitcnt vmcnt(0)" ::: "memory");  // loads ~1 compute old
      __builtin_amdgcn_s_barrier();
      __builtin_amdgcn_sched_barrier(0);
      cur ^= 1;
    }
  }

  // epilogue: D elem (row = quad*4 + r2, col = l16) within each 16x16 tile
#pragma unroll
  for (int mt = 0; mt < 4; mt++) {
#pragma unroll
    for (int nt = 0; nt < 4; nt++) {
      int row0 = bm * 128 + wm * 64 + mt * 16 + quad * 4;
      int col = bn * 128 + wn * 64 + nt * 16 + l16;
      if (F32OUT) {
        float* cp = (float*)Cv + (long)row0 * N + col;
#pragma unroll
        for (int r2 = 0; r2 < 4; r2++)
          cp[(long)r2 * N] = acc[mt][nt][r2];
      } else {
        unsigned short* cp = (unsigned short*)Cv + (long)row0 * N + col;
#pragma unroll
        for (int r2 = 0; r2 < 4; r2++)
          cp[(long)r2 * N] = f2b(acc[mt][nt][r2]);
      }
    }
  }
}

// ---------------------------------------------------------------------------
// Causal attention, one block per (b,h). QKV: [16384][1536] bf16.
// All 256 K-rows + V staged ONCE (one barrier), then wave w independently
// processes 32-row q-tile pair {w, 7-w}: (w+1)+(8-w) = 9 chunk-32s per wave.
// Kl: packed rows, global-side XOR swizzle (gll16-compatible). Vt: rows
// padded to 264 shorts. Pl: stride 40. Fixed-shift softmax (p = exp(s),
// fp32 row-sum normalize at end) — validated absmax 0.0156.
// ---------------------------------------------------------------------------
__global__ __launch_bounds__(256, 2) void attn(const unsigned short* __restrict__ QKV,
                                               unsigned short* __restrict__ AO) {
  const int bh = blockIdx.x;
  const int b = bh >> 3, h = bh & 7;
  const int tid = threadIdx.x;
  const int wave = tid >> 6, lane = tid & 63;
  const int quad = lane >> 4, l16 = lane & 15;

  __shared__ unsigned short Kl[256 * 64];    // [j][cg], stored cg holds global cg^(j&7)
  __shared__ unsigned short Vt[64 * 264];    // [d][j], padded rows
  __shared__ unsigned short Pl[4][32 * 40];  // per-wave P [trow][col], padded

  const unsigned short* Qb = QKV + (long)b * 256 * 1536 + h * 64;
  const unsigned short* Kb = Qb + 512;
  const unsigned short* Vb = Qb + 1024;

  // ---- stage K: 32 segs x 8 rows, gll16 with global-side swizzle ----
  {
    int r = lane >> 3, cg = lane & 7;
#pragma unroll
    for (int s = 0; s < 8; s++) {
      int seg = wave * 8 + s;
      gll16(Kb + (long)(seg * 8 + r) * 1536 + ((cg ^ r) * 8), Kl + seg * 512);
    }
  }
  // ---- stage V transposed: thread tid owns V row j=tid ----
  {
    int j = tid;
    const unsigned short* vp = Vb + (long)j * 1536;
#pragma unroll
    for (int g = 0; g < 8; g++) {
      union { u32x4 v; unsigned short s[8]; } d;
      d.v = *(const u32x4*)(vp + g * 8);
#pragma unroll
      for (int q = 0; q < 8; q++)
        Vt[(g * 8 + q) * 264 + j] = d.s[q];
    }
  }
  // ---- Q fragments for this wave's tile pair ----
  const int tiles[2] = {wave, 7 - wave};
  bf16x8 qf[2][2][2];  // [ti][kc][mt]
#pragma unroll
  for (int ti = 0; ti < 2; ti++)
#pragma unroll
    for (int kc = 0; kc < 2; kc++)
#pragma unroll
      for (int mt = 0; mt < 2; mt++)
        qf[ti][kc][mt] = *(const bf16x8*)(Qb +
            (long)(tiles[ti] * 32 + mt * 16 + l16) * 1536 + kc * 32 + quad * 8);

  __syncthreads();  // drains gll16 vmcnt + V/Q visibility; the ONLY barrier

  f32x4 O[2][2][4] = {};      // [ti][mt][dt]
  float lsum[2][2][4] = {};   // [ti][mt][r]
  const float scale = 0.044194173824159216f;  // 1/sqrt(512)

#pragma unroll
  for (int ti = 0; ti < 2; ti++) {
    const int t = tiles[ti];
    for (int c32 = 0; c32 <= t; c32++) {       // wave-uniform trip count
      // ---- S = Q K^T for 32 rows x 32 cols ----
      f32x4 S[2][2] = {};                      // [mt][st]
#pragma unroll
      for (int kc = 0; kc < 2; kc++) {
        bf16x8 kbf[2];
#pragma unroll
        for (int st = 0; st < 2; st++) {
          int jrow = c32 * 32 + st * 16 + l16;
          kbf[st] = *(const bf16x8*)(Kl + jrow * 64 + (((kc * 4 + quad) ^ (jrow & 7)) * 8));
        }
#pragma unroll
        for (int mt = 0; mt < 2; mt++)
#pragma unroll
          for (int st = 0; st < 2; st++)
            S[mt][st] = __builtin_amdgcn_mfma_f32_16x16x32_bf16(qf[ti][kc][mt], kbf[st], S[mt][st], 0, 0, 0);
      }
      // ---- softmax numerator, P -> LDS (C-layout -> row-major) ----
      const bool diag = (c32 == t);
#pragma unroll
      for (int mt = 0; mt < 2; mt++)
#pragma unroll
        for (int st = 0; st < 2; st++)
#pragma unroll
          for (int r = 0; r < 4; r++) {
            int trow = mt * 16 + quad * 4 + r;         // row within 32-row tile
            float p = __expf(S[mt][st][r] * scale);
            if (diag && (st * 16 + l16 > trow)) p = 0.0f;
            lsum[ti][mt][r] += p;
            Pl[wave][trow * 40 + st * 16 + l16] = f2b(p);
          }
      // ---- O += P V  (same-wave LDS RAW: compiler lgkmcnt, no barrier) ----
      bf16x8 pa[2], vbf[4];
#pragma unroll
      for (int mt = 0; mt < 2; mt++)
        pa[mt] = *(const bf16x8*)(&Pl[wave][(mt * 16 + l16) * 40 + quad * 8]);
#pragma unroll
      for (int dt = 0; dt < 4; dt++)
        vbf[dt] = *(const bf16x8*)(Vt + (dt * 16 + l16) * 264 + c32 * 32 + quad * 8);
#pragma unroll
      for (int mt = 0; mt < 2; mt++)
#pragma unroll
        for (int dt = 0; dt < 4; dt++)
          O[ti][mt][dt] = __builtin_amdgcn_mfma_f32_16x16x32_bf16(pa[mt], vbf[dt], O[ti][mt][dt], 0, 0, 0);
    }
  }

  // ---- normalize by row sum (16 lanes of a quad hold one row's 16 cols) ----
  float linv[2][2][4];
#pragma unroll
  for (int ti = 0; ti < 2; ti++)
#pragma unroll
    for (int mt = 0; mt < 2; mt++)
#pragma unroll
      for (int r = 0; r < 4; r++) {
        float s = lsum[ti][mt][r];
        s += __shfl_xor(s, 1); s += __shfl_xor(s, 2);
        s += __shfl_xor(s, 4); s += __shfl_xor(s, 8);
        linv[ti][mt][r] = 1.0f / s;
      }
#pragma unroll
  for (int ti = 0; ti < 2; ti++)
#pragma unroll
    for (int mt = 0; mt < 2; mt++)
#pragma unroll
      for (int dt = 0; dt < 4; dt++)
#pragma unroll
        for (int r = 0; r < 4; r++) {
          int t_ = tiles[ti] * 32 + mt * 16 + quad * 4 + r;
          int d = dt * 16 + l16;
          AO[(long)(b * 256 + t_) * 512 + h * 64 + d] = f2b(O[ti][mt][dt][r] * linv[ti][mt][r]);
        }
}

// ---------------------------------------------------------------------------
extern "C" void kernel_launch(void* const* d_in, const int* in_sizes, int n_in,
                              void* d_out, int out_size, void* d_ws, size_t ws_size,
                              hipStream_t stream) {
  const float* x  = (const float*)d_in[0];   // [16384][512] fp32
  const float* Wq = (const float*)d_in[1];   // [8][512][64] fp32
  const float* Wk = (const float*)d_in[2];
  const float* Wv = (const float*)d_in[3];
  const float* Wo = (const float*)d_in[4];   // [512][512] fp32

  unsigned short* Wt  = (unsigned short*)d_ws;                 // 1536*512
  unsigned short* WoT = Wt + 1536 * 512;                       // 512*512
  unsigned short* xb  = WoT + 512 * 512;                       // 16384*512
  unsigned short* QKV = xb + (long)16384 * 512;                // 16384*1536
  unsigned short* AO  = QKV + (long)16384 * 1536;              // 16384*512
  float* out = (float*)d_out;                                  // [16384][512] fp32

  prep<<<8448, 256, 0, stream>>>(x, Wq, Wk, Wv, Wo, xb, Wt, WoT);

  gemm_bt<0><<<1536, 256, 0, stream>>>(xb, Wt, (void*)QKV, 1536);

  attn<<<512, 256, 0, stream>>>(QKV, AO);

  gemm_bt<1><<<512, 256, 0, stream>>>(AO, WoT, (void*)out, 512);
}

// Round 7
// 148.243 us; speedup vs baseline: 1.0970x; 1.0542x over previous
//
#include <hip/hip_runtime.h>
#include <hip/hip_bf16.h>

typedef __attribute__((ext_vector_type(4))) float f32x4;
typedef __attribute__((ext_vector_type(8))) short bf16x8;
typedef __attribute__((ext_vector_type(4))) short s16x4;
typedef __attribute__((ext_vector_type(4))) unsigned int u32x4;

#define DEV static __device__ __forceinline__

// fp32 -> bf16 round-to-nearest-even (finite values only)
DEV unsigned short f2b(float f) {
  union { float f; unsigned int u; } v; v.f = f;
  unsigned int u = v.u;
  return (unsigned short)((u + 0x7fffu + ((u >> 16) & 1u)) >> 16);
}

// async global->LDS, 16B per lane; lds base wave-uniform, lanes land at base + lane*16
DEV void gll16(const void* g, void* l) {
  __builtin_amdgcn_global_load_lds((__attribute__((address_space(1))) void*)g,
                                   (__attribute__((address_space(3))) void*)l,
                                   16, 0, 0);
}

// ---------------------------------------------------------------------------
// prep: fp32 -> bf16 conversion + weight repack (verified, unchanged).
// Blocks 0..8191: x conversion. 8192..8383: Wt tiles. 8384..8447: WoT tiles.
// ---------------------------------------------------------------------------
__global__ __launch_bounds__(256) void prep(const float* __restrict__ x,
                                            const float* __restrict__ Wq,
                                            const float* __restrict__ Wk,
                                            const float* __restrict__ Wv,
                                            const float* __restrict__ Wo,
                                            unsigned short* __restrict__ xb,
                                            unsigned short* __restrict__ Wt,
                                            unsigned short* __restrict__ WoT) {
  const int bid = blockIdx.x;
  if (bid < 8192) {                                    // x: 8388608 elems / 4
    int id = bid * 256 + threadIdx.x;
    f32x4 v = *(const f32x4*)(x + (long)id * 4);
    s16x4 o;
    o.x = (short)f2b(v.x); o.y = (short)f2b(v.y);
    o.z = (short)f2b(v.z); o.w = (short)f2b(v.w);
    *(s16x4*)(xb + (long)id * 4) = o;
    return;
  }

  __shared__ unsigned int L[64 * 65];
  const int tx = threadIdx.x & 63;
  const int ty = threadIdx.x >> 6;

  int tb = bid - 8192;
  if (tb < 192) {
    int proj = tb >> 6, h = (tb >> 3) & 7, c0 = (tb & 7) << 6;
    const float* W = (proj == 0) ? Wq : ((proj == 1) ? Wk : Wv);
    const float* base = W + (long)h * 32768 + (long)c0 * 64;  // [c][d]
#pragma unroll
    for (int i = 0; i < 16; i++) {
      int c = ty + i * 4;
      L[tx * 65 + c] = f2b(base[(long)c * 64 + tx]);    // L[d][c]
    }
    __syncthreads();
    unsigned short* out = Wt + ((long)(proj * 512 + h * 64)) * 512 + c0;
#pragma unroll
    for (int i = 0; i < 16; i++) {
      int d = ty + i * 4;
      out[(long)d * 512 + tx] = (unsigned short)L[d * 65 + tx];
    }
  } else {
    int t = tb - 192;
    int n0 = (t >> 3) << 6, c0 = (t & 7) << 6;
#pragma unroll
    for (int i = 0; i < 16; i++) {
      int c = ty + i * 4;
      L[tx * 65 + c] = f2b(Wo[(long)(c0 + c) * 512 + n0 + tx]);  // L[n][c]
    }
    __syncthreads();
    unsigned short* out = WoT + (long)n0 * 512 + c0;
#pragma unroll
    for (int i = 0; i < 16; i++) {
      int n = ty + i * 4;
      out[(long)n * 512 + tx] = (unsigned short)L[n * 65 + tx];
    }
  }
}

// ---------------------------------------------------------------------------
// Fused QKV-projection + causal attention. One block per (b,h), 512 threads
// (8 waves), 1 block/CU (119.8 KB LDS), grid 512 = 2 CU-rounds.
//
// P1: QKV = xb[b] @ Wt_h^T (256 x 192, K=512, BK=64). Verified gll16 staging
//     (cg^(row&7) swizzle) + 2-phase dbuf loop (at 1 block/CU there is no
//     cross-block overlap, so the dbuf genuinely hides staging latency).
//     Waves: 2M x 4N, 128x48 out each, acc[8][3].
// scatter: acc -> LDS in attn-native layouts, SAME values as old global QKV:
//     Q,K: [256][64] with cg^(row&7) swizzle; V: Vt[d][j] transposed.
// P2: verified attn loop, tile pair {u,7-u} per wave PAIR, chunks split by
//     c32 parity (each wave 4-5 chunks — balanced on any wave->SIMD map).
// P3: combine partial O/lsum of each pair through f32 scratch aliased over
//     the then-dead Q/K regions; normalize; write AO.
//
// LDS map (shorts): Qs[0,16384) Kl[16384,32768) Vt[32768,49664) Pl[49664,59904)
//   P1 aliases: As{0,16384} x2, Bs{32768,45056} x2 (dead before scatter).
//   P3 aliases: Oscr f32[16384] over Qs+Kl; Lscr over Pl.
// XCD swizzle: all 8 heads of a batch land on one XCD (xb[b] fetched once).
// ---------------------------------------------------------------------------
__global__ __launch_bounds__(512, 2) void qkv_attn(const unsigned short* __restrict__ xb,
                                                   const unsigned short* __restrict__ Wt,
                                                   unsigned short* __restrict__ AO) {
  __shared__ unsigned short SM[59904];
  const int QS_OFF = 0, KL_OFF = 16384, VT_OFF = 32768, PL_OFF = 49664;
  const int ASO[2] = {0, 16384};
  const int BSO[2] = {32768, 45056};

  const int tid = threadIdx.x;
  const int wave = tid >> 6, lane = tid & 63;
  const int quad = lane >> 4, l16 = lane & 15;

  // XCD-bijective swizzle (nwg = 512, q = 64, r = 0)
  const int xcd = blockIdx.x & 7, ci = blockIdx.x >> 3;
  const int wg = xcd * 64 + ci;
  const int b = wg >> 3, h = wg & 7;

  const unsigned short* Ag = xb + (long)b * 256 * 512;   // [256][512]

  // ---------------- P1: QKV GEMM ----------------
  const int wm = wave >> 2, wn = wave & 3;               // 2M x 4N
  const int srow = lane >> 3;                            // row within 8-row seg
  const int scol = ((lane & 7) ^ srow) * 8;              // pre-swizzled global col

  f32x4 acc[8][3] = {};

  auto stage = [&](int kk, int buf) {
#pragma unroll
    for (int s = 0; s < 4; s++) {                        // A: 32 segs x 8 rows
      int seg = wave * 4 + s;
      int row = seg * 8 + srow;
      gll16(Ag + (long)row * 512 + kk + scol, SM + ASO[buf] + seg * 512);
    }
#pragma unroll
    for (int s = 0; s < 3; s++) {                        // B: 24 segs x 8 rows
      int seg = wave * 3 + s;
      int proj = seg >> 3;
      int wrow = proj * 512 + h * 64 + (seg & 7) * 8 + srow;
      gll16(Wt + (long)wrow * 512 + kk + scol, SM + BSO[buf] + seg * 512);
    }
  };

  auto compute = [&](int buf) {
#pragma unroll
    for (int kc = 0; kc < 2; kc++) {
      const int rq = (((kc * 4 + quad) ^ (l16 & 7)) * 8);
      bf16x8 af[8], bfv[3];
#pragma unroll
      for (int mt = 0; mt < 8; mt++)
        af[mt] = *(const bf16x8*)(SM + ASO[buf] + (wm * 128 + mt * 16 + l16) * 64 + rq);
#pragma unroll
      for (int nt = 0; nt < 3; nt++)
        bfv[nt] = *(const bf16x8*)(SM + BSO[buf] + (wn * 48 + nt * 16 + l16) * 64 + rq);
#pragma unroll
      for (int mt = 0; mt < 8; mt++)
#pragma unroll
        for (int nt = 0; nt < 3; nt++)
          acc[mt][nt] = __builtin_amdgcn_mfma_f32_16x16x32_bf16(af[mt], bfv[nt], acc[mt][nt], 0, 0, 0);
    }
  };

  stage(0, 0);
  asm volatile("s_waitcnt vmcnt(0)" ::: "memory");
  __builtin_amdgcn_s_barrier();
  __builtin_amdgcn_sched_barrier(0);

  int cur = 0;
#pragma unroll
  for (int t = 0; t < 8; t++) {
    if (t < 7) stage((t + 1) * 64, cur ^ 1);
    __builtin_amdgcn_sched_barrier(0);
    compute(cur);
    if (t < 7) {
      asm volatile("s_waitcnt vmcnt(0)" ::: "memory");
      __builtin_amdgcn_s_barrier();
      __builtin_amdgcn_sched_barrier(0);
      cur ^= 1;
    }
  }

  // ---------------- scatter acc -> Q/K/V LDS ----------------
  __syncthreads();   // all waves' staging reads retired (scatter aliases them)
#pragma unroll
  for (int mt = 0; mt < 8; mt++) {
#pragma unroll
    for (int nt = 0; nt < 3; nt++) {
      const int g = wn * 48 + nt * 16;          // col base; +l16 per lane
      const int proj = g >> 6;                  // uniform over the 16-col tile
      const int j0 = wm * 128 + mt * 16 + quad * 4;
      if (proj == 2) {
        int dcol = (g & 63) + l16;
        unsigned int w0 = (unsigned)f2b(acc[mt][nt][0]) | ((unsigned)f2b(acc[mt][nt][1]) << 16);
        unsigned int w1 = (unsigned)f2b(acc[mt][nt][2]) | ((unsigned)f2b(acc[mt][nt][3]) << 16);
        unsigned int* vp = (unsigned int*)(SM + VT_OFF + dcol * 264 + j0);
        vp[0] = w0; vp[1] = w1;                 // Vt[dcol][j0..j0+3]
      } else {
        unsigned short* base = SM + (proj ? KL_OFF : QS_OFF);
        int d = (g & 63) + l16;
        int dhi = d >> 3, dlo = d & 7;
#pragma unroll
        for (int r2 = 0; r2 < 4; r2++) {
          int j = j0 + r2;
          base[j * 64 + ((dhi ^ (j & 7)) * 8) + dlo] = f2b(acc[mt][nt][r2]);
        }
      }
    }
  }
  __syncthreads();   // Q/K/V published to all waves

  // ---------------- P2: attention ----------------
  const int u = wave >> 1, par = wave & 1;     // pair u, parity split
  const int tiles2[2] = {u, 7 - u};

  bf16x8 qf[2][2][2];  // [ti][kc][mt]
#pragma unroll
  for (int ti = 0; ti < 2; ti++)
#pragma unroll
    for (int kc = 0; kc < 2; kc++)
#pragma unroll
      for (int mt = 0; mt < 2; mt++) {
        int row = tiles2[ti] * 32 + mt * 16 + l16;
        qf[ti][kc][mt] = *(const bf16x8*)(SM + QS_OFF + row * 64 +
                                          (((kc * 4 + quad) ^ (row & 7)) * 8));
      }

  f32x4 O[2][2][4] = {};      // [ti][mt][dt]
  float lsum[2][2][4] = {};   // [ti][mt][r]
  const float scale = 0.044194173824159216f;  // 1/sqrt(512)

#pragma unroll
  for (int ti = 0; ti < 2; ti++) {
    const int t = tiles2[ti];
    for (int c32 = par; c32 <= t; c32 += 2) {  // wave-uniform trip count
      f32x4 S[2][2] = {};
#pragma unroll
      for (int kc = 0; kc < 2; kc++) {
        bf16x8 kbf[2];
#pragma unroll
        for (int st = 0; st < 2; st++) {
          int jrow = c32 * 32 + st * 16 + l16;
          kbf[st] = *(const bf16x8*)(SM + KL_OFF + jrow * 64 +
                                     (((kc * 4 + quad) ^ (jrow & 7)) * 8));
        }
#pragma unroll
        for (int mt = 0; mt < 2; mt++)
#pragma unroll
          for (int st = 0; st < 2; st++)
            S[mt][st] = __builtin_amdgcn_mfma_f32_16x16x32_bf16(qf[ti][kc][mt], kbf[st], S[mt][st], 0, 0, 0);
      }
      const bool diag = (c32 == t);
#pragma unroll
      for (int mt = 0; mt < 2; mt++)
#pragma unroll
        for (int st = 0; st < 2; st++)
#pragma unroll
          for (int r = 0; r < 4; r++) {
            int trow = mt * 16 + quad * 4 + r;
            float p = __expf(S[mt][st][r] * scale);
            if (diag && (st * 16 + l16 > trow)) p = 0.0f;
            lsum[ti][mt][r] += p;
            SM[PL_OFF + wave * 1280 + trow * 40 + st * 16 + l16] = f2b(p);
          }
      bf16x8 pa[2], vbf[4];
#pragma unroll
      for (int mt = 0; mt < 2; mt++)
        pa[mt] = *(const bf16x8*)(SM + PL_OFF + wave * 1280 + (mt * 16 + l16) * 40 + quad * 8);
#pragma unroll
      for (int dt = 0; dt < 4; dt++)
        vbf[dt] = *(const bf16x8*)(SM + VT_OFF + (dt * 16 + l16) * 264 + c32 * 32 + quad * 8);
#pragma unroll
      for (int mt = 0; mt < 2; mt++)
#pragma unroll
        for (int dt = 0; dt < 4; dt++)
          O[ti][mt][dt] = __builtin_amdgcn_mfma_f32_16x16x32_bf16(pa[mt], vbf[dt], O[ti][mt][dt], 0, 0, 0);
    }
  }

  // ---------------- P3: pair combine + normalize + write ----------------
  float lred[2][2][4];
#pragma unroll
  for (int ti = 0; ti < 2; ti++)
#pragma unroll
    for (int mt = 0; mt < 2; mt++)
#pragma unroll
      for (int r = 0; r < 4; r++) {
        float s = lsum[ti][mt][r];
        s += __shfl_xor(s, 1); s += __shfl_xor(s, 2);
        s += __shfl_xor(s, 4); s += __shfl_xor(s, 8);
        lred[ti][mt][r] = s;
      }

  __syncthreads();   // all waves done reading Qs/Kl (scratch aliases them)

  float* Oscr = (float*)SM;                       // 4 pairs x 4096 f32 (64 KB)
  float* Lscr = (float*)(SM + PL_OFF);            // 4 pairs x 64 f32

  if (par == 1) {
#pragma unroll
    for (int ti = 0; ti < 2; ti++)
#pragma unroll
      for (int mt = 0; mt < 2; mt++)
#pragma unroll
        for (int dt = 0; dt < 4; dt++)
#pragma unroll
          for (int r = 0; r < 4; r++)
            Oscr[u * 4096 + (ti * 32 + mt * 16 + quad * 4 + r) * 64 + dt * 16 + l16] = O[ti][mt][dt][r];
    if (l16 == 0)
#pragma unroll
      for (int ti = 0; ti < 2; ti++)
#pragma unroll
        for (int mt = 0; mt < 2; mt++)
#pragma unroll
          for (int r = 0; r < 4; r++)
            Lscr[u * 64 + ti * 32 + mt * 16 + quad * 4 + r] = lred[ti][mt][r];
  }
  __syncthreads();

  if (par == 0) {
    float linv[2][2][4];
#pragma unroll
    for (int ti = 0; ti < 2; ti++)
#pragma unroll
      for (int mt = 0; mt < 2; mt++)
#pragma unroll
        for (int r = 0; r < 4; r++)
          linv[ti][mt][r] = 1.0f / (lred[ti][mt][r] +
                                    Lscr[u * 64 + ti * 32 + mt * 16 + quad * 4 + r]);
#pragma unroll
    for (int ti = 0; ti < 2; ti++)
#pragma unroll
      for (int mt = 0; mt < 2; mt++)
#pragma unroll
        for (int dt = 0; dt < 4; dt++)
#pragma unroll
          for (int r = 0; r < 4; r++) {
            float o = O[ti][mt][dt][r] +
                      Oscr[u * 4096 + (ti * 32 + mt * 16 + quad * 4 + r) * 64 + dt * 16 + l16];
            int t_ = tiles2[ti] * 32 + mt * 16 + quad * 4 + r;
            int d = dt * 16 + l16;
            AO[(long)(b * 256 + t_) * 512 + h * 64 + d] = f2b(o * linv[ti][mt][r]);
          }
  }
}

// ---------------------------------------------------------------------------
// C[M x N] = A[M x 512] * BT[N x 512]^T  — round-6 verified 2-phase kernel.
// Now used only for the output projection (AO @ WoT -> out, N=512).
// ---------------------------------------------------------------------------
template <int F32OUT>
__global__ __launch_bounds__(256, 2) void gemm_bt(const unsigned short* __restrict__ A,
                                                  const unsigned short* __restrict__ BT,
                                                  void* __restrict__ Cv,
                                                  int N) {
  const int K = 512;
  __shared__ unsigned short As[2][128 * 64];
  __shared__ unsigned short Bs[2][128 * 64];

  const int tid = threadIdx.x;
  const int wave = tid >> 6, lane = tid & 63;
  const int quad = lane >> 4, l16 = lane & 15;
  const int wm = wave >> 1, wn = wave & 1;

  const int NB = N >> 7;
  const int nwg = gridDim.x;
  const int q = nwg >> 3, r = nwg & 7;
  const int xcd = blockIdx.x & 7, ci = blockIdx.x >> 3;
  const int wg = (xcd < r ? xcd * (q + 1) : r * (q + 1) + (xcd - r) * q) + ci;
  const int bn = wg % NB;
  const int bm = wg / NB;

  const int srow = lane >> 3;
  const int scol = ((lane & 7) ^ srow) * 8;

  f32x4 acc[4][4] = {};

  auto stage = [&](int kk, int buf) {
#pragma unroll
    for (int s = 0; s < 4; s++) {
      int seg = wave * 4 + s;
      int row = seg * 8 + srow;
      gll16(A + (long)(bm * 128 + row) * K + kk + scol, &As[buf][seg * 512]);
      gll16(BT + (long)(bn * 128 + row) * K + kk + scol, &Bs[buf][seg * 512]);
    }
  };

  auto compute = [&](int buf) {
#pragma unroll
    for (int kc = 0; kc < 2; kc++) {
      const int rq = (((kc * 4 + quad) ^ (l16 & 7)) * 8);
      bf16x8 af[4], bfv[4];
#pragma unroll
      for (int mt = 0; mt < 4; mt++)
        af[mt] = *(const bf16x8*)(&As[buf][(wm * 64 + mt * 16 + l16) * 64 + rq]);
#pragma unroll
      for (int nt = 0; nt < 4; nt++)
        bfv[nt] = *(const bf16x8*)(&Bs[buf][(wn * 64 + nt * 16 + l16) * 64 + rq]);
#pragma unroll
      for (int mt = 0; mt < 4; mt++)
#pragma unroll
        for (int nt = 0; nt < 4; nt++)
          acc[mt][nt] = __builtin_amdgcn_mfma_f32_16x16x32_bf16(af[mt], bfv[nt], acc[mt][nt], 0, 0, 0);
    }
  };

  stage(0, 0);
  asm volatile("s_waitcnt vmcnt(0)" ::: "memory");
  __builtin_amdgcn_s_barrier();
  __builtin_amdgcn_sched_barrier(0);

  int cur = 0;
#pragma unroll
  for (int t = 0; t < 8; t++) {
    if (t < 7) stage((t + 1) * 64, cur ^ 1);
    __builtin_amdgcn_sched_barrier(0);
    compute(cur);
    if (t < 7) {
      asm volatile("s_waitcnt vmcnt(0)" ::: "memory");
      __builtin_amdgcn_s_barrier();
      __builtin_amdgcn_sched_barrier(0);
      cur ^= 1;
    }
  }

#pragma unroll
  for (int mt = 0; mt < 4; mt++) {
#pragma unroll
    for (int nt = 0; nt < 4; nt++) {
      int row0 = bm * 128 + wm * 64 + mt * 16 + quad * 4;
      int col = bn * 128 + wn * 64 + nt * 16 + l16;
      if (F32OUT) {
        float* cp = (float*)Cv + (long)row0 * N + col;
#pragma unroll
        for (int r2 = 0; r2 < 4; r2++)
          cp[(long)r2 * N] = acc[mt][nt][r2];
      } else {
        unsigned short* cp = (unsigned short*)Cv + (long)row0 * N + col;
#pragma unroll
        for (int r2 = 0; r2 < 4; r2++)
          cp[(long)r2 * N] = f2b(acc[mt][nt][r2]);
      }
    }
  }
}

// ---------------------------------------------------------------------------
extern "C" void kernel_launch(void* const* d_in, const int* in_sizes, int n_in,
                              void* d_out, int out_size, void* d_ws, size_t ws_size,
                              hipStream_t stream) {
  const float* x  = (const float*)d_in[0];   // [16384][512] fp32
  const float* Wq = (const float*)d_in[1];   // [8][512][64] fp32
  const float* Wk = (const float*)d_in[2];
  const float* Wv = (const float*)d_in[3];
  const float* Wo = (const float*)d_in[4];   // [512][512] fp32

  unsigned short* Wt  = (unsigned short*)d_ws;                 // 1536*512
  unsigned short* WoT = Wt + 1536 * 512;                       // 512*512
  unsigned short* xb  = WoT + 512 * 512;                       // 16384*512
  unsigned short* AO  = xb + (long)16384 * 512;                // 16384*512
  float* out = (float*)d_out;                                  // [16384][512] fp32

  prep<<<8448, 256, 0, stream>>>(x, Wq, Wk, Wv, Wo, xb, Wt, WoT);

  qkv_attn<<<512, 512, 0, stream>>>(xb, Wt, AO);

  gemm_bt<1><<<512, 256, 0, stream>>>(AO, WoT, (void*)out, 512);
}